// Round 1
// baseline (396.678 us; speedup 1.0000x reference)
//
#include <hip/hip_runtime.h>
#include <stdint.h>

#define N_EDGES 500000

typedef __attribute__((ext_vector_type(8))) short short8;
typedef __attribute__((ext_vector_type(4))) float floatx4;

__device__ __forceinline__ uint16_t f2bf(float f) {
  union { float f; uint32_t u; } cv; cv.f = f;
  uint32_t u = cv.u;
  return (uint16_t)((u + 0x7FFFu + ((u >> 16) & 1u)) >> 16);
}

__device__ __forceinline__ float lrelu(float v) { return v >= 0.0f ? v : 0.001f * v; }

// ---- prep: bf16 transpose of weights + fold bond-emb block of layer0 into BE0 table ----
__global__ void prep_kernel(const float* __restrict__ W0, const float* __restrict__ b0,
                            const float* __restrict__ W1, const float* __restrict__ W2,
                            const float* __restrict__ bemb,
                            uint16_t* __restrict__ w0t, uint16_t* __restrict__ w1t,
                            uint16_t* __restrict__ w2t, float* __restrict__ be0) {
  int id = blockIdx.x * 256 + threadIdx.x;
  if (id < 40960) {                       // W0t': [n][k'], k'<256 -> W0 rows 0..255 (emb_i|emb_j),
    int n = id / 320, k = id % 320;       //        k' in [256,320) -> W0 rows 320..383 (smear)
    int ks = (k < 256) ? k : (k + 64);
    w0t[id] = f2bf(W0[ks * 128 + n]);
  } else if (id < 57344) {
    int t = id - 40960; int n = t >> 7, k = t & 127;
    w1t[t] = f2bf(W1[k * 128 + n]);
  } else if (id < 73728) {
    int t = id - 57344; int n = t >> 7, k = t & 127;
    w2t[t] = f2bf(W2[k * 128 + n]);
  } else if (id < 74240) {                // BE0[t][n] = bond_emb[t] @ W0[256:320] + b0  (fp32)
    int t = id - 73728; int ty = t >> 7, n = t & 127;
    float s = b0[n];
    for (int kk = 0; kk < 64; ++kk) s += bemb[ty * 64 + kk] * W0[(256 + kk) * 128 + n];
    be0[t] = s;
  }
}

__global__ void copy_pos_kernel(const float* __restrict__ pos, float* __restrict__ out, int n) {
  int id = blockIdx.x * 256 + threadIdx.x;
  if (id < n) out[id] = pos[id];
}

// One K-step: stage 32x128 weight slice into LDS (stride 40 -> bank-uniform), then
// each wave does 8 MFMA over its 16 rows. 2 barriers per kstep (m97-style).
template <int NKS, int WSTRIDE, int ABASE>
__device__ __forceinline__ void gemm_layer(const uint16_t* __restrict__ Wt,
                                           const uint16_t* feat, uint16_t* kslice,
                                           int tid, int arow, int quad, int n15,
                                           floatx4* acc) {
  for (int ks = 0; ks < NKS; ++ks) {
    __syncthreads();
#pragma unroll
    for (int rep = 0; rep < 2; ++rep) {
      int c = rep * 256 + tid;
      int n = c >> 2, part = c & 3;
      uint4 v = *(const uint4*)(Wt + n * WSTRIDE + ks * 32 + part * 8);
      *(uint4*)(kslice + n * 40 + part * 8) = v;
    }
    __syncthreads();
    // A[m=lane&15][k=quad*8+j], contiguous 16B from feat row
    short8 a = *(const short8*)(feat + arow * 328 + ABASE + ks * 32 + quad * 8);
#pragma unroll
    for (int nt = 0; nt < 8; ++nt) {
      // B[k=quad*8+j][n=lane&15] from transposed slice row n
      short8 b = *(const short8*)(kslice + (nt * 16 + n15) * 40 + quad * 8);
      acc[nt] = __builtin_amdgcn_mfma_f32_16x16x32_bf16(a, b, acc[nt], 0, 0, 0);
    }
  }
  __syncthreads();  // all waves done reading before epilogue overwrites feat
}

__launch_bounds__(256, 3)
__global__ void bond_mlp_kernel(const float* __restrict__ x, const float* __restrict__ nemb,
                                const int* __restrict__ bidx, const int* __restrict__ btyp,
                                const uint16_t* __restrict__ w0t, const uint16_t* __restrict__ w1t,
                                const uint16_t* __restrict__ w2t, const float* __restrict__ be0,
                                const float* __restrict__ b1, const float* __restrict__ ln1w,
                                const float* __restrict__ ln1b,
                                const float* __restrict__ b2, const float* __restrict__ ln2w,
                                const float* __restrict__ ln2b,
                                const float* __restrict__ Wo, const float* __restrict__ bo,
                                float* __restrict__ out) {
  // stride 328: row stride 656B = 164 banks ≡ 4 mod 32 -> 2-way (free); 16B-aligned rows
  __shared__ __align__(16) uint16_t feat[64 * 328];      // 41984 B
  __shared__ __align__(16) uint16_t kslice[128 * 40];    // 10240 B
  __shared__ float u_lds[64][3];
  __shared__ int ij_lds[64][2];
  __shared__ int type_lds[64];

  const int tid = threadIdx.x;
  const int lane = tid & 63;
  const int wave = tid >> 6;
  const int n15 = lane & 15;
  const int quad = lane >> 4;

  // ---------------- phase 1: gather + smear -> feat (bf16) ----------------
  {
    const int le = lane >> 2, sub = lane & 3;   // 4 lanes per edge
    const int row = wave * 16 + le;
    const int ge = blockIdx.x * 64 + row;
    const bool valid = ge < N_EDGES;
    int vi = 0, vj = 0, bt = 0;
    if (valid) { vi = bidx[2 * ge]; vj = bidx[2 * ge + 1]; bt = btyp[ge]; }
    float dx, dy, dz;
    if (valid) {
      dx = x[3 * vi]     - x[3 * vj];
      dy = x[3 * vi + 1] - x[3 * vj + 1];
      dz = x[3 * vi + 2] - x[3 * vj + 2];
    } else { dx = 1.0f; dy = 0.0f; dz = 0.0f; }   // keep finite for dead rows
    float dist = sqrtf(dx * dx + dy * dy + dz * dz);
    float rinv = 1.0f / dist;
    if (sub == 0) {
      u_lds[row][0] = dx * rinv; u_lds[row][1] = dy * rinv; u_lds[row][2] = dz * rinv;
      ij_lds[row][0] = vi; ij_lds[row][1] = vj; type_lds[row] = bt;
    }
    const float4* pei = (const float4*)(nemb + (size_t)vi * 128);
    const float4* pej = (const float4*)(nemb + (size_t)vj * 128);
#pragma unroll
    for (int g = 0; g < 4; ++g) {                 // emb_i -> cols [0,128)
      float4 a = pei[sub * 8 + g * 2], b = pei[sub * 8 + g * 2 + 1];
      uint4 pk;
      pk.x = f2bf(a.x) | ((uint32_t)f2bf(a.y) << 16);
      pk.y = f2bf(a.z) | ((uint32_t)f2bf(a.w) << 16);
      pk.z = f2bf(b.x) | ((uint32_t)f2bf(b.y) << 16);
      pk.w = f2bf(b.z) | ((uint32_t)f2bf(b.w) << 16);
      *(uint4*)(feat + row * 328 + sub * 32 + g * 8) = pk;
    }
#pragma unroll
    for (int g = 0; g < 4; ++g) {                 // emb_j -> cols [128,256)
      float4 a = pej[sub * 8 + g * 2], b = pej[sub * 8 + g * 2 + 1];
      uint4 pk;
      pk.x = f2bf(a.x) | ((uint32_t)f2bf(a.y) << 16);
      pk.y = f2bf(a.z) | ((uint32_t)f2bf(a.w) << 16);
      pk.z = f2bf(b.x) | ((uint32_t)f2bf(b.y) << 16);
      pk.w = f2bf(b.z) | ((uint32_t)f2bf(b.w) << 16);
      *(uint4*)(feat + row * 328 + 128 + sub * 32 + g * 8) = pk;
    }
    // smear -> cols [256,320)
    const float delta = 20.0f / 62.0f;
    const float coeff = -0.5f / (delta * delta);
    float sv[16]; float ssum = 0.0f;
#pragma unroll
    for (int t = 0; t < 16; ++t) {
      int kk = sub * 16 + t;
      float v;
      if (kk < 63) { float d = dist - (float)kk * delta; v = __expf(coeff * d * d); }
      else v = (dist >= 20.0f) ? 1.0f : 0.0f;
      sv[t] = v; ssum += v;
    }
    ssum += __shfl_xor(ssum, 1);
    ssum += __shfl_xor(ssum, 2);
    float sinv = 1.0f / ssum;
#pragma unroll
    for (int g = 0; g < 2; ++g) {
      uint4 pk;
      pk.x = f2bf(sv[g*8+0]*sinv) | ((uint32_t)f2bf(sv[g*8+1]*sinv) << 16);
      pk.y = f2bf(sv[g*8+2]*sinv) | ((uint32_t)f2bf(sv[g*8+3]*sinv) << 16);
      pk.z = f2bf(sv[g*8+4]*sinv) | ((uint32_t)f2bf(sv[g*8+5]*sinv) << 16);
      pk.w = f2bf(sv[g*8+6]*sinv) | ((uint32_t)f2bf(sv[g*8+7]*sinv) << 16);
      *(uint4*)(feat + row * 328 + 256 + sub * 16 + g * 8) = pk;
    }
  }
  // gemm_layer opens with __syncthreads -> phase-1 writes visible

  const int arow = wave * 16 + n15;         // A-fragment row
  const int rowb = wave * 16 + quad * 4;    // C rows rowb..rowb+3 (reg 0..3)

  floatx4 acc[8];
#pragma unroll
  for (int nt = 0; nt < 8; ++nt) acc[nt] = (floatx4){0.f, 0.f, 0.f, 0.f};
  gemm_layer<10, 320, 0>(w0t, feat, kslice, tid, arow, quad, n15, acc);

  // epilogue 0: + BE0[type] (b0 folded), lrelu -> h0 in feat cols [0,128)
  {
    int t4[4];
#pragma unroll
    for (int r = 0; r < 4; ++r) t4[r] = type_lds[rowb + r];
#pragma unroll
    for (int nt = 0; nt < 8; ++nt) {
      int col = nt * 16 + n15;
#pragma unroll
      for (int r = 0; r < 4; ++r) {
        float v = acc[nt][r] + be0[t4[r] * 128 + col];
        feat[(rowb + r) * 328 + col] = f2bf(lrelu(v));
      }
    }
  }

#pragma unroll
  for (int nt = 0; nt < 8; ++nt) acc[nt] = (floatx4){0.f, 0.f, 0.f, 0.f};
  gemm_layer<4, 128, 0>(w1t, feat, kslice, tid, arow, quad, n15, acc);

  // epilogue 1: +b1, LN(ln1) via quad shuffles, lrelu -> h1 in feat cols [128,256)
  {
    float bv[8], wv[8], bb[8];
#pragma unroll
    for (int nt = 0; nt < 8; ++nt) {
      int col = nt * 16 + n15;
      bv[nt] = b1[col]; wv[nt] = ln1w[col]; bb[nt] = ln1b[col];
    }
    float s[4] = {0,0,0,0}, q[4] = {0,0,0,0};
#pragma unroll
    for (int nt = 0; nt < 8; ++nt)
#pragma unroll
      for (int r = 0; r < 4; ++r) { float v = acc[nt][r] + bv[nt]; s[r] += v; q[r] += v * v; }
#pragma unroll
    for (int m = 1; m <= 8; m <<= 1)
#pragma unroll
      for (int r = 0; r < 4; ++r) { s[r] += __shfl_xor(s[r], m); q[r] += __shfl_xor(q[r], m); }
    float mean[4], rstd[4];
#pragma unroll
    for (int r = 0; r < 4; ++r) {
      mean[r] = s[r] * (1.0f / 128.0f);
      float var = q[r] * (1.0f / 128.0f) - mean[r] * mean[r];
      rstd[r] = rsqrtf(var + 1e-5f);
    }
#pragma unroll
    for (int nt = 0; nt < 8; ++nt) {
      int col = nt * 16 + n15;
#pragma unroll
      for (int r = 0; r < 4; ++r) {
        float v = acc[nt][r] + bv[nt];
        float vn = (v - mean[r]) * rstd[r] * wv[nt] + bb[nt];
        feat[(rowb + r) * 328 + 128 + col] = f2bf(lrelu(vn));
      }
    }
  }

#pragma unroll
  for (int nt = 0; nt < 8; ++nt) acc[nt] = (floatx4){0.f, 0.f, 0.f, 0.f};
  gemm_layer<4, 128, 128>(w2t, feat, kslice, tid, arow, quad, n15, acc);

  // epilogue 2: +b2, LN(ln2), lrelu, force = h@Wo + bo (quad-reduced), scatter atomics
  {
    float bv[8], wv[8], bb[8], wo0[8], wo1[8];
#pragma unroll
    for (int nt = 0; nt < 8; ++nt) {
      int col = nt * 16 + n15;
      bv[nt] = b2[col]; wv[nt] = ln2w[col]; bb[nt] = ln2b[col];
      wo0[nt] = Wo[2 * col]; wo1[nt] = Wo[2 * col + 1];
    }
    float s[4] = {0,0,0,0}, q[4] = {0,0,0,0};
#pragma unroll
    for (int nt = 0; nt < 8; ++nt)
#pragma unroll
      for (int r = 0; r < 4; ++r) { float v = acc[nt][r] + bv[nt]; s[r] += v; q[r] += v * v; }
#pragma unroll
    for (int m = 1; m <= 8; m <<= 1)
#pragma unroll
      for (int r = 0; r < 4; ++r) { s[r] += __shfl_xor(s[r], m); q[r] += __shfl_xor(q[r], m); }
    float mean[4], rstd[4];
#pragma unroll
    for (int r = 0; r < 4; ++r) {
      mean[r] = s[r] * (1.0f / 128.0f);
      float var = q[r] * (1.0f / 128.0f) - mean[r] * mean[r];
      rstd[r] = rsqrtf(var + 1e-5f);
    }
    float f0[4] = {0,0,0,0}, f1[4] = {0,0,0,0};
#pragma unroll
    for (int nt = 0; nt < 8; ++nt)
#pragma unroll
      for (int r = 0; r < 4; ++r) {
        float v = acc[nt][r] + bv[nt];
        float vn = lrelu((v - mean[r]) * rstd[r] * wv[nt] + bb[nt]);
        f0[r] += vn * wo0[nt];
        f1[r] += vn * wo1[nt];
      }
#pragma unroll
    for (int m = 1; m <= 8; m <<= 1)
#pragma unroll
      for (int r = 0; r < 4; ++r) { f0[r] += __shfl_xor(f0[r], m); f1[r] += __shfl_xor(f1[r], m); }

    if (n15 < 4) {
      int row2 = rowb + n15;
      int ge2 = blockIdx.x * 64 + row2;
      if (ge2 < N_EDGES) {
        float F0 = (n15 == 0) ? f0[0] : (n15 == 1) ? f0[1] : (n15 == 2) ? f0[2] : f0[3];
        float F1 = (n15 == 0) ? f1[0] : (n15 == 1) ? f1[1] : (n15 == 2) ? f1[2] : f1[3];
        F0 += bo[0]; F1 += bo[1];
        float ux = u_lds[row2][0], uy = u_lds[row2][1], uz = u_lds[row2][2];
        int ii = ij_lds[row2][0], jj = ij_lds[row2][1];
        float c0 = 0.5f * F0;          // STEP * force0, along +u
        float c1 = -0.5f * F1;         // STEP * force1, along -u
        atomicAdd(out + 3 * ii,     c0 * ux);
        atomicAdd(out + 3 * ii + 1, c0 * uy);
        atomicAdd(out + 3 * ii + 2, c0 * uz);
        atomicAdd(out + 3 * jj,     c1 * ux);
        atomicAdd(out + 3 * jj + 1, c1 * uy);
        atomicAdd(out + 3 * jj + 2, c1 * uz);
      }
    }
  }
}

extern "C" void kernel_launch(void* const* d_in, const int* in_sizes, int n_in,
                              void* d_out, int out_size, void* d_ws, size_t ws_size,
                              hipStream_t stream) {
  const float* x    = (const float*)d_in[0];
  const float* pos  = (const float*)d_in[1];
  const float* nemb = (const float*)d_in[2];
  const int*   bidx = (const int*)d_in[3];
  const int*   btyp = (const int*)d_in[4];
  const float* bemb = (const float*)d_in[5];
  const float* W0   = (const float*)d_in[6];
  const float* b0   = (const float*)d_in[7];
  const float* W1   = (const float*)d_in[8];
  const float* b1   = (const float*)d_in[9];
  const float* ln1w = (const float*)d_in[10];
  const float* ln1b = (const float*)d_in[11];
  const float* W2   = (const float*)d_in[12];
  const float* b2   = (const float*)d_in[13];
  const float* ln2w = (const float*)d_in[14];
  const float* ln2b = (const float*)d_in[15];
  const float* Wo   = (const float*)d_in[16];
  const float* bo   = (const float*)d_in[17];
  float* out = (float*)d_out;

  uint16_t* w0t = (uint16_t*)d_ws;            // 40960 bf16  (320x128 transposed W0, bond block removed)
  uint16_t* w1t = w0t + 40960;                // 16384 bf16
  uint16_t* w2t = w1t + 16384;                // 16384 bf16
  float*    be0 = (float*)(w2t + 16384);      // 4x128 f32   (bond path + b0 folded)

  prep_kernel<<<290, 256, 0, stream>>>(W0, b0, W1, W2, bemb, w0t, w1t, w2t, be0);
  copy_pos_kernel<<<(out_size + 255) / 256, 256, 0, stream>>>(pos, out, out_size);
  bond_mlp_kernel<<<(N_EDGES + 63) / 64, 256, 0, stream>>>(
      x, nemb, bidx, btyp, w0t, w1t, w2t, be0,
      b1, ln1w, ln1b, b2, ln2w, ln2b, Wo, bo, out);
}